// Round 7
// baseline (145.045 us; speedup 1.0000x reference)
//
#include <hip/hip_runtime.h>

// R14: R13 retry — poly exp2 with FOLD-PROOF range reduction.
// R13 post-mortem: absmax 0.1 failure = signature of f==0; the magic-constant
// rounding n=(a+M)-M was reassociated to n=a by fast-math, collapsing the
// poly to 2^round(a) (each exp off by up to 2^+-0.5). Fix: n = rintf(a)
// (v_rndne_f32, not algebraically foldable), f = a-n, scale via INTEGER path
// s = bitcast(((int)n << 23) + 0x3F800000) (v_cvt_i32_f32 + v_lshl_add_u32,
// immune to fast-math). ~14 insts/pair ~ 28cy replacing 2 trans ops.
// Learned from R13: actual absmax threshold is 3.39e-2 (8x headroom over
// the 3.9e-3 baseline); poly rel err 2.4e-6 is negligible.
// Hypothesis unchanged: wall pinned ~54us across R7/R11/R12 while VALU issue
// varies +-7% -> binding resource is the trans pipe (866 trans/wave x ~32cy
// x 4 waves ~ 86% of wall). attn1's 512 exps = 65% of trans -> poly moves
// them to the full-rate pipe.
// Decision rule: 44-48us+VALUBusy up = trans-bound confirmed (then port
// attn2/MLP exps too); flat = partial (exp ~14-16cy); >=57us = trans cheap,
// revert R11, declare plateau structural.
// Tripwires: WRITE=2048, VGPR<=128, absmax ~0.004 (<< 3.39e-2).
// Ledger: occupancy dead (R9); spill cliff VGPR<=44-needed (R8); SGPR
// ceiling ~1 weight group (R10); ILP-interleave neutral (R12).

typedef float v2f __attribute__((ext_vector_type(2)));

#define LOG2E 1.44269504088896340736f
#define ROWS 2

__device__ __forceinline__ float rcpf(float a) { return __builtin_amdgcn_rcpf(a); }

#if __has_builtin(__builtin_amdgcn_exp2f)
__device__ __forceinline__ float exp2_fast(float a) { return __builtin_amdgcn_exp2f(a); }
#else
__device__ __forceinline__ float exp2_fast(float a) { return __expf(0.6931471805599453f * a); }
#endif

// Packed exp2 for a pair of args (each <= 0), on the full-rate pipe.
// n = rintf(a)  -> v_rndne_f32 (hardware round, cannot be reassociated away)
// f = a - n in [-0.5, 0.5]; 2^f by degree-5 Taylor Horner (v_pk_fma_f32);
// 2^n by integer exponent assembly from (int)n (fast-math-immune).
__device__ __forceinline__ v2f exp2_pk(v2f a) {
    // clamp so n >= -126 (scale stays normal; true value < 1e-38 ~ 0 anyway)
    v2f ac; ac[0] = fmaxf(a[0], -126.0f); ac[1] = fmaxf(a[1], -126.0f);
    const float n0 = rintf(ac[0]);               // v_rndne_f32
    const float n1 = rintf(ac[1]);
    v2f nn; nn[0] = n0; nn[1] = n1;
    v2f f = ac - nn;                             // exact, f in [-0.5, 0.5]
    // 2^f = exp(f ln2), Taylor deg-5, rel err ~2.4e-6 on this range
    v2f p;
    p[0] = 0.00133335581f; p[1] = 0.00133335581f;
    v2f c4; c4[0] = 0.00961812911f; c4[1] = 0.00961812911f;
    v2f c3; c3[0] = 0.05550410866f; c3[1] = 0.05550410866f;
    v2f c2; c2[0] = 0.24022650696f; c2[1] = 0.24022650696f;
    v2f c1; c1[0] = 0.69314718056f; c1[1] = 0.69314718056f;
    v2f c0; c0[0] = 1.0f;           c0[1] = 1.0f;
    p = p * f + c4;                              // v_pk_fma_f32 chain
    p = p * f + c3;
    p = p * f + c2;
    p = p * f + c1;
    p = p * f + c0;
    // scale = 2^n via integer exponent assembly: ((int)n + 127) << 23
    const int ni0 = (int)n0;                     // v_cvt_i32_f32 (exact: n integral)
    const int ni1 = (int)n1;
    v2f s;
    s[0] = __builtin_bit_cast(float, (ni0 << 23) + 0x3F800000);  // v_lshl_add_u32
    s[1] = __builtin_bit_cast(float, (ni1 << 23) + 0x3F800000);
    return p * s;
}

__global__ __launch_bounds__(256, 4) void fused_attn_mlp(
    const float* __restrict__ x,
    const float* __restrict__ wq,
    const float* __restrict__ wk,
    const float* __restrict__ wv,
    const float* __restrict__ Wh,
    const float* __restrict__ bh,
    const float* __restrict__ Wo,
    const float* __restrict__ bo,
    float* __restrict__ out,
    int B)
{
    const int t = threadIdx.x;
    const int b0 = blockIdx.x * (256 * ROWS) + t;

    // Clamped indices: loads always in-bounds (no exec-mask machinery);
    // stores masked by valid[]. Correct for any B >= 1.
    bool valid[ROWS];
    int bidx[ROWS];
    #pragma unroll
    for (int r = 0; r < ROWS; ++r) {
        const int b = b0 + r * 256;
        valid[r] = b < B;
        bidx[r] = valid[r] ? b : (B - 1);
    }

    // ---- issue x loads first (VMEM latency hides under s_load setup) ----
    float4 xraw[ROWS][4];
    #pragma unroll
    for (int r = 0; r < ROWS; ++r) {
        const float4* xr = reinterpret_cast<const float4*>(x) + (size_t)bidx[r] * 4;
        xraw[r][0] = xr[0]; xraw[r][1] = xr[1]; xraw[r][2] = xr[2]; xraw[r][3] = xr[3];
    }

    // ---- unpack x rows ----
    float xs[ROWS][16];
    v2f xv2[ROWS][8];
    #pragma unroll
    for (int r = 0; r < ROWS; ++r) {
        xs[r][0]=xraw[r][0].x; xs[r][1]=xraw[r][0].y; xs[r][2]=xraw[r][0].z; xs[r][3]=xraw[r][0].w;
        xs[r][4]=xraw[r][1].x; xs[r][5]=xraw[r][1].y; xs[r][6]=xraw[r][1].z; xs[r][7]=xraw[r][1].w;
        xs[r][8]=xraw[r][2].x; xs[r][9]=xraw[r][2].y; xs[r][10]=xraw[r][2].z; xs[r][11]=xraw[r][2].w;
        xs[r][12]=xraw[r][3].x; xs[r][13]=xraw[r][3].y; xs[r][14]=xraw[r][3].z; xs[r][15]=xraw[r][3].w;
        #pragma unroll
        for (int p = 0; p < 8; ++p) { v2f v; v[0]=xs[r][2*p]; v[1]=xs[r][2*p+1]; xv2[r][p]=v; }
    }

    // ---- attention block 1 (D=16), exp2 domain, POLY exp on full-rate pipe ----
    const float kq1 = wk[0] * wq[0] * LOG2E;
    const float v1  = wv[0];

    float xmx[ROWS], xmn[ROWS];
    #pragma unroll
    for (int r = 0; r < ROWS; ++r) {
        float mx = xs[r][0], mn = xs[r][0];
        #pragma unroll
        for (int i = 1; i < 16; ++i) { mx = fmaxf(mx, xs[r][i]); mn = fminf(mn, xs[r][i]); }
        xmx[r] = mx; xmn[r] = mn;
    }

    v2f o1v[ROWS][8];
    #pragma unroll
    for (int r = 0; r < ROWS; ++r)
        #pragma unroll
        for (int p = 0; p < 8; ++p) o1v[r][p] = (v2f)(0.f);

    #pragma unroll
    for (int i = 0; i < 16; ++i) {
        v2f e2[ROWS][8];
        float w[ROWS];
        #pragma unroll
        for (int r = 0; r < ROWS; ++r) {
            const float c = kq1 * xs[r][i];
            const float m = fmaxf(c * xmx[r], c * xmn[r]);   // exact attained max -> args <= 0
            v2f cc; cc[0]=c; cc[1]=c;
            v2f mm; mm[0]=m; mm[1]=m;
            #pragma unroll
            for (int p = 0; p < 8; ++p) {
                v2f a = cc * xv2[r][p] - mm;                 // v_pk_fma_f32
                e2[r][p] = exp2_pk(a);                       // packed poly, no trans
            }
            v2f s01 = e2[r][0] + e2[r][1];
            v2f s23 = e2[r][2] + e2[r][3];
            v2f s45 = e2[r][4] + e2[r][5];
            v2f s67 = e2[r][6] + e2[r][7];
            v2f sv  = (s01 + s23) + (s45 + s67);
            w[r] = xs[r][i] * rcpf(sv[0] + sv[1]);           // v1 deferred to epilogue
        }
        #pragma unroll
        for (int r = 0; r < ROWS; ++r) {
            v2f ww; ww[0]=w[r]; ww[1]=w[r];
            #pragma unroll
            for (int p = 0; p < 8; ++p) o1v[r][p] += ww * e2[r][p];
        }
    }

    // deferred v1 scale: one 8-pk pass per row instead of 16 in-loop muls
    {
        v2f v1v; v1v[0]=v1; v1v[1]=v1;
        #pragma unroll
        for (int r = 0; r < ROWS; ++r)
            #pragma unroll
            for (int p = 0; p < 8; ++p) o1v[r][p] *= v1v;
    }

    // ---- fused MLP: 16 -> 64 sigmoid -> 8. Weights read at UNIFORM global
    //      indices -> s_load (scalar pipe). R7 structure: per-hh inline
    //      loads, unroll 2. Sigmoid rcps Montgomery-batched. ----
    v2f x2v[ROWS][4];
    #pragma unroll
    for (int r = 0; r < ROWS; ++r)
        #pragma unroll
        for (int p = 0; p < 4; ++p) { v2f v; v[0]=bo[2*p]; v[1]=bo[2*p+1]; x2v[r][p]=v; }

    const v2f* Wh2 = reinterpret_cast<const v2f*>(Wh);   // [64][8] pairs

    #pragma unroll 2
    for (int g = 0; g < 16; ++g) {
        float apre[ROWS][4];
        #pragma unroll
        for (int hh = 0; hh < 4; ++hh) {
            const int h = g * 4 + hh;
            v2f whr[8];
            #pragma unroll
            for (int p = 0; p < 8; ++p) whr[p] = Wh2[h * 8 + p];   // uniform -> s_load
            const float bhh = bh[h];
            #pragma unroll
            for (int r = 0; r < ROWS; ++r) {
                v2f acc = whr[0] * o1v[r][0];
                #pragma unroll
                for (int p = 1; p < 8; ++p) acc += whr[p] * o1v[r][p];
                apre[r][hh] = acc[0] + acc[1] + bhh;
            }
        }
        float sg[ROWS][4];
        #pragma unroll
        for (int r = 0; r < ROWS; ++r) {
            // clamp inert for a > -20.8 (sigma < 1e-9 there); keeps
            // d = 1+2^la <= 1+2^30, so prod4 <= 2^121 (no overflow).
            float d[4];
            #pragma unroll
            for (int hh = 0; hh < 4; ++hh) {
                const float la = fminf(-apre[r][hh] * LOG2E, 30.f);
                d[hh] = 1.f + exp2_fast(la);
            }
            const float p01  = d[0] * d[1];
            const float p012 = p01 * d[2];
            const float rq   = rcpf(p012 * d[3]);
            const float i3 = rq * p012;
            const float tq = rq * d[3];      // 1/(d0 d1 d2)
            const float i2 = tq * p01;
            const float t2 = tq * d[2];      // 1/(d0 d1)
            sg[r][0] = t2 * d[1];
            sg[r][1] = t2 * d[0];
            sg[r][2] = i2;
            sg[r][3] = i3;
        }
        // x2[o] += Wo[o][h] * sg[h] for the 4 h's of this group; Wo accessed
        // at uniform indices (o compile-time, h unrolled) -> s_load.
        #pragma unroll
        for (int hh = 0; hh < 4; ++hh) {
            const int h = g * 4 + hh;
            #pragma unroll
            for (int p = 0; p < 4; ++p) {      // p = output pair (o = 2p, 2p+1)
                v2f wo2;
                wo2[0] = Wo[(2 * p) * 64 + h];       // uniform scalar loads
                wo2[1] = Wo[(2 * p + 1) * 64 + h];
                #pragma unroll
                for (int r = 0; r < ROWS; ++r) {
                    v2f sgv; sgv[0] = sg[r][hh]; sgv[1] = sg[r][hh];
                    x2v[r][p] += wo2 * sgv;
                }
            }
        }
    }

    // ---- attention block 2 (D=8), exp2 domain; LOG2E folded into o2 ----
    const float kq2 = wk[1] * wq[1] * LOG2E;
    const float v2s = wv[1] * LOG2E;

    float ys[ROWS][8];
    float ymx[ROWS], ymn[ROWS];
    #pragma unroll
    for (int r = 0; r < ROWS; ++r) {
        #pragma unroll
        for (int i = 0; i < 8; ++i) ys[r][i] = x2v[r][i >> 1][i & 1];
        float mx = ys[r][0], mn = ys[r][0];
        #pragma unroll
        for (int i = 1; i < 8; ++i) { mx = fmaxf(mx, ys[r][i]); mn = fminf(mn, ys[r][i]); }
        ymx[r] = mx; ymn[r] = mn;
    }

    v2f o2v[ROWS][4];
    #pragma unroll
    for (int r = 0; r < ROWS; ++r)
        #pragma unroll
        for (int p = 0; p < 4; ++p) o2v[r][p] = (v2f)(0.f);

    #pragma unroll
    for (int i = 0; i < 8; ++i) {
        v2f e2[ROWS][4];
        float w[ROWS];
        #pragma unroll
        for (int r = 0; r < ROWS; ++r) {
            const float c = kq2 * ys[r][i];
            const float m = fmaxf(c * ymx[r], c * ymn[r]);
            v2f cc; cc[0]=c; cc[1]=c;
            v2f mm; mm[0]=m; mm[1]=m;
            #pragma unroll
            for (int p = 0; p < 4; ++p) {
                v2f a = cc * x2v[r][p] - mm;
                v2f e; e[0] = exp2_fast(a[0]); e[1] = exp2_fast(a[1]);
                e2[r][p] = e;
            }
            v2f sv = (e2[r][0] + e2[r][1]) + (e2[r][2] + e2[r][3]);
            w[r] = v2s * ys[r][i] * rcpf(sv[0] + sv[1]);
        }
        #pragma unroll
        for (int r = 0; r < ROWS; ++r) {
            v2f ww; ww[0]=w[r]; ww[1]=w[r];
            #pragma unroll
            for (int p = 0; p < 4; ++p) o2v[r][p] += ww * e2[r][p];
        }
    }

    // ---- final softmax (log2 domain) + dot with x[8:16] ----
    #pragma unroll
    for (int r = 0; r < ROWS; ++r) {
        float o2s[8];
        #pragma unroll
        for (int i = 0; i < 8; ++i) o2s[i] = o2v[r][i >> 1][i & 1];
        float m2 = o2s[0];
        #pragma unroll
        for (int i = 1; i < 8; ++i) m2 = fmaxf(m2, o2s[i]);
        v2f mm2; mm2[0]=m2; mm2[1]=m2;
        v2f se = (v2f)(0.f), de = (v2f)(0.f);
        #pragma unroll
        for (int p = 0; p < 4; ++p) {
            v2f a = o2v[r][p] - mm2;
            v2f e; e[0] = exp2_fast(a[0]); e[1] = exp2_fast(a[1]);
            se += e;
            v2f xp; xp[0]=xs[r][8+2*p]; xp[1]=xs[r][9+2*p];
            de += xp * e;
        }
        if (valid[r]) out[b0 + r * 256] = (de[0] + de[1]) * rcpf(se[0] + se[1]);
    }
}

extern "C" void kernel_launch(void* const* d_in, const int* in_sizes, int n_in,
                              void* d_out, int out_size, void* d_ws, size_t ws_size,
                              hipStream_t stream) {
    const float* x  = (const float*)d_in[0];
    const float* wq = (const float*)d_in[1];
    const float* wk = (const float*)d_in[2];
    const float* wv = (const float*)d_in[3];
    const float* Wh = (const float*)d_in[4];
    const float* bh = (const float*)d_in[5];
    const float* Wo = (const float*)d_in[6];
    const float* bo = (const float*)d_in[7];
    float* out = (float*)d_out;

    const int B = in_sizes[0] / 16;
    const int block = 256;
    const int rows_per_block = block * ROWS;
    const int grid = (B + rows_per_block - 1) / rows_per_block;
    fused_attn_mlp<<<grid, block, 0, stream>>>(x, wq, wk, wv, Wh, bh, Wo, bo, out, B);
}

// Round 10
// 128.482 us; speedup vs baseline: 1.1289x; 1.1289x over previous
//
#include <hip/hip_runtime.h>

// R17: second resubmission of the R11 champion — R15 and R16 both died to
// "MI355X container failed twice" (broker-side infra; no kernel executed).
// Source is byte-equivalent to R11, which passed at 53.8us/dispatch
// (124.3us bench) in its original harness run. A kernel cannot cause a
// container-acquisition failure; resubmitting unchanged keeps the session
// anchored to the verified optimum.
// Machine model established across rounds:
//   wall ≈ VALU-busy + ~19us fixed idle
//   R11: 35.2+18.6=53.8 | R12: 37.1 absorbed | R14: 58.0+19.2=77.2 | R9: idle grew
// Busy term: trans-dominated, exp count 392/row algorithmically minimal
// (symmetric-triangle cut register-infeasible f32); hw v_exp_f32 cheap
// (R14 poly regressed 43%). Idle term resisted: TLP (R9 worse), ILP (R12
// neutral), SGPR hoisting (R10 cliff), VGPR squeeze (R8 spill), LDS (prior
// session all worse). Every lever tested; floor confirmed from all sides.
// Ledger: occupancy dead (R9); spill cliff VGPR<44-needed (R8); SGPR
// ceiling ~1 weight group (R10); ILP-interleave neutral (R12); poly exp
// regresses 43% (R14); absmax threshold 3.39e-2 (8x headroom, unused).
// Kept: s_load weight path (no LDS/barrier), exp2-domain softmax/sigmoid
// with attained-max shift, Montgomery-batched sigmoid rcps, packed fp32
// (v_pk_fma_f32), tree sums, clamped-index loads, deferred v1, x loads first.

typedef float v2f __attribute__((ext_vector_type(2)));

#define LOG2E 1.44269504088896340736f
#define ROWS 2

__device__ __forceinline__ float rcpf(float a) { return __builtin_amdgcn_rcpf(a); }

#if __has_builtin(__builtin_amdgcn_exp2f)
__device__ __forceinline__ float exp2_fast(float a) { return __builtin_amdgcn_exp2f(a); }
#else
__device__ __forceinline__ float exp2_fast(float a) { return __expf(0.6931471805599453f * a); }
#endif

__global__ __launch_bounds__(256, 4) void fused_attn_mlp(
    const float* __restrict__ x,
    const float* __restrict__ wq,
    const float* __restrict__ wk,
    const float* __restrict__ wv,
    const float* __restrict__ Wh,
    const float* __restrict__ bh,
    const float* __restrict__ Wo,
    const float* __restrict__ bo,
    float* __restrict__ out,
    int B)
{
    const int t = threadIdx.x;
    const int b0 = blockIdx.x * (256 * ROWS) + t;

    // Clamped indices: loads always in-bounds (no exec-mask machinery);
    // stores masked by valid[]. Correct for any B >= 1.
    bool valid[ROWS];
    int bidx[ROWS];
    #pragma unroll
    for (int r = 0; r < ROWS; ++r) {
        const int b = b0 + r * 256;
        valid[r] = b < B;
        bidx[r] = valid[r] ? b : (B - 1);
    }

    // ---- issue x loads first (VMEM latency hides under s_load setup) ----
    float4 xraw[ROWS][4];
    #pragma unroll
    for (int r = 0; r < ROWS; ++r) {
        const float4* xr = reinterpret_cast<const float4*>(x) + (size_t)bidx[r] * 4;
        xraw[r][0] = xr[0]; xraw[r][1] = xr[1]; xraw[r][2] = xr[2]; xraw[r][3] = xr[3];
    }

    // ---- unpack x rows ----
    float xs[ROWS][16];
    v2f xv2[ROWS][8];
    #pragma unroll
    for (int r = 0; r < ROWS; ++r) {
        xs[r][0]=xraw[r][0].x; xs[r][1]=xraw[r][0].y; xs[r][2]=xraw[r][0].z; xs[r][3]=xraw[r][0].w;
        xs[r][4]=xraw[r][1].x; xs[r][5]=xraw[r][1].y; xs[r][6]=xraw[r][1].z; xs[r][7]=xraw[r][1].w;
        xs[r][8]=xraw[r][2].x; xs[r][9]=xraw[r][2].y; xs[r][10]=xraw[r][2].z; xs[r][11]=xraw[r][2].w;
        xs[r][12]=xraw[r][3].x; xs[r][13]=xraw[r][3].y; xs[r][14]=xraw[r][3].z; xs[r][15]=xraw[r][3].w;
        #pragma unroll
        for (int p = 0; p < 8; ++p) { v2f v; v[0]=xs[r][2*p]; v[1]=xs[r][2*p+1]; xv2[r][p]=v; }
    }

    // ---- attention block 1 (D=16), exp2 domain ----
    const float kq1 = wk[0] * wq[0] * LOG2E;
    const float v1  = wv[0];

    float xmx[ROWS], xmn[ROWS];
    #pragma unroll
    for (int r = 0; r < ROWS; ++r) {
        float mx = xs[r][0], mn = xs[r][0];
        #pragma unroll
        for (int i = 1; i < 16; ++i) { mx = fmaxf(mx, xs[r][i]); mn = fminf(mn, xs[r][i]); }
        xmx[r] = mx; xmn[r] = mn;
    }

    v2f o1v[ROWS][8];
    #pragma unroll
    for (int r = 0; r < ROWS; ++r)
        #pragma unroll
        for (int p = 0; p < 8; ++p) o1v[r][p] = (v2f)(0.f);

    #pragma unroll
    for (int i = 0; i < 16; ++i) {
        v2f e2[ROWS][8];
        float w[ROWS];
        #pragma unroll
        for (int r = 0; r < ROWS; ++r) {
            const float c = kq1 * xs[r][i];
            const float m = fmaxf(c * xmx[r], c * xmn[r]);   // exact attained max -> args <= 0
            v2f cc; cc[0]=c; cc[1]=c;
            v2f mm; mm[0]=m; mm[1]=m;
            #pragma unroll
            for (int p = 0; p < 8; ++p) {
                v2f a = cc * xv2[r][p] - mm;                 // v_pk_fma_f32
                v2f e; e[0] = exp2_fast(a[0]); e[1] = exp2_fast(a[1]);
                e2[r][p] = e;
            }
            v2f s01 = e2[r][0] + e2[r][1];
            v2f s23 = e2[r][2] + e2[r][3];
            v2f s45 = e2[r][4] + e2[r][5];
            v2f s67 = e2[r][6] + e2[r][7];
            v2f sv  = (s01 + s23) + (s45 + s67);
            w[r] = xs[r][i] * rcpf(sv[0] + sv[1]);           // v1 deferred to epilogue
        }
        #pragma unroll
        for (int r = 0; r < ROWS; ++r) {
            v2f ww; ww[0]=w[r]; ww[1]=w[r];
            #pragma unroll
            for (int p = 0; p < 8; ++p) o1v[r][p] += ww * e2[r][p];
        }
    }

    // deferred v1 scale: one 8-pk pass per row instead of 16 in-loop muls
    {
        v2f v1v; v1v[0]=v1; v1v[1]=v1;
        #pragma unroll
        for (int r = 0; r < ROWS; ++r)
            #pragma unroll
            for (int p = 0; p < 8; ++p) o1v[r][p] *= v1v;
    }

    // ---- fused MLP: 16 -> 64 sigmoid -> 8. Weights read at UNIFORM global
    //      indices -> s_load (scalar pipe). Per-hh inline loads, unroll 2
    //      (R7/R11 verified optimum). Sigmoid rcps Montgomery-batched. ----
    v2f x2v[ROWS][4];
    #pragma unroll
    for (int r = 0; r < ROWS; ++r)
        #pragma unroll
        for (int p = 0; p < 4; ++p) { v2f v; v[0]=bo[2*p]; v[1]=bo[2*p+1]; x2v[r][p]=v; }

    const v2f* Wh2 = reinterpret_cast<const v2f*>(Wh);   // [64][8] pairs

    #pragma unroll 2
    for (int g = 0; g < 16; ++g) {
        float apre[ROWS][4];
        #pragma unroll
        for (int hh = 0; hh < 4; ++hh) {
            const int h = g * 4 + hh;
            v2f whr[8];
            #pragma unroll
            for (int p = 0; p < 8; ++p) whr[p] = Wh2[h * 8 + p];   // uniform -> s_load
            const float bhh = bh[h];
            #pragma unroll
            for (int r = 0; r < ROWS; ++r) {
                v2f acc = whr[0] * o1v[r][0];
                #pragma unroll
                for (int p = 1; p < 8; ++p) acc += whr[p] * o1v[r][p];
                apre[r][hh] = acc[0] + acc[1] + bhh;
            }
        }
        float sg[ROWS][4];
        #pragma unroll
        for (int r = 0; r < ROWS; ++r) {
            // clamp inert for a > -20.8 (sigma < 1e-9 there); keeps
            // d = 1+2^la <= 1+2^30, so prod4 <= 2^121 (no overflow).
            float d[4];
            #pragma unroll
            for (int hh = 0; hh < 4; ++hh) {
                const float la = fminf(-apre[r][hh] * LOG2E, 30.f);
                d[hh] = 1.f + exp2_fast(la);
            }
            const float p01  = d[0] * d[1];
            const float p012 = p01 * d[2];
            const float rq   = rcpf(p012 * d[3]);
            const float i3 = rq * p012;
            const float tq = rq * d[3];      // 1/(d0 d1 d2)
            const float i2 = tq * p01;
            const float t2 = tq * d[2];      // 1/(d0 d1)
            sg[r][0] = t2 * d[1];
            sg[r][1] = t2 * d[0];
            sg[r][2] = i2;
            sg[r][3] = i3;
        }
        // x2[o] += Wo[o][h] * sg[h] for the 4 h's of this group; Wo accessed
        // at uniform indices (o compile-time, h unrolled) -> s_load.
        #pragma unroll
        for (int hh = 0; hh < 4; ++hh) {
            const int h = g * 4 + hh;
            #pragma unroll
            for (int p = 0; p < 4; ++p) {      // p = output pair (o = 2p, 2p+1)
                v2f wo2;
                wo2[0] = Wo[(2 * p) * 64 + h];       // uniform scalar loads
                wo2[1] = Wo[(2 * p + 1) * 64 + h];
                #pragma unroll
                for (int r = 0; r < ROWS; ++r) {
                    v2f sgv; sgv[0] = sg[r][hh]; sgv[1] = sg[r][hh];
                    x2v[r][p] += wo2 * sgv;
                }
            }
        }
    }

    // ---- attention block 2 (D=8), exp2 domain; LOG2E folded into o2 ----
    const float kq2 = wk[1] * wq[1] * LOG2E;
    const float v2s = wv[1] * LOG2E;

    float ys[ROWS][8];
    float ymx[ROWS], ymn[ROWS];
    #pragma unroll
    for (int r = 0; r < ROWS; ++r) {
        #pragma unroll
        for (int i = 0; i < 8; ++i) ys[r][i] = x2v[r][i >> 1][i & 1];
        float mx = ys[r][0], mn = ys[r][0];
        #pragma unroll
        for (int i = 1; i < 8; ++i) { mx = fmaxf(mx, ys[r][i]); mn = fminf(mn, ys[r][i]); }
        ymx[r] = mx; ymn[r] = mn;
    }

    v2f o2v[ROWS][4];
    #pragma unroll
    for (int r = 0; r < ROWS; ++r)
        #pragma unroll
        for (int p = 0; p < 4; ++p) o2v[r][p] = (v2f)(0.f);

    #pragma unroll
    for (int i = 0; i < 8; ++i) {
        v2f e2[ROWS][4];
        float w[ROWS];
        #pragma unroll
        for (int r = 0; r < ROWS; ++r) {
            const float c = kq2 * ys[r][i];
            const float m = fmaxf(c * ymx[r], c * ymn[r]);
            v2f cc; cc[0]=c; cc[1]=c;
            v2f mm; mm[0]=m; mm[1]=m;
            #pragma unroll
            for (int p = 0; p < 4; ++p) {
                v2f a = cc * x2v[r][p] - mm;
                v2f e; e[0] = exp2_fast(a[0]); e[1] = exp2_fast(a[1]);
                e2[r][p] = e;
            }
            v2f sv = (e2[r][0] + e2[r][1]) + (e2[r][2] + e2[r][3]);
            w[r] = v2s * ys[r][i] * rcpf(sv[0] + sv[1]);
        }
        #pragma unroll
        for (int r = 0; r < ROWS; ++r) {
            v2f ww; ww[0]=w[r]; ww[1]=w[r];
            #pragma unroll
            for (int p = 0; p < 4; ++p) o2v[r][p] += ww * e2[r][p];
        }
    }

    // ---- final softmax (log2 domain) + dot with x[8:16] ----
    #pragma unroll
    for (int r = 0; r < ROWS; ++r) {
        float o2s[8];
        #pragma unroll
        for (int i = 0; i < 8; ++i) o2s[i] = o2v[r][i >> 1][i & 1];
        float m2 = o2s[0];
        #pragma unroll
        for (int i = 1; i < 8; ++i) m2 = fmaxf(m2, o2s[i]);
        v2f mm2; mm2[0]=m2; mm2[1]=m2;
        v2f se = (v2f)(0.f), de = (v2f)(0.f);
        #pragma unroll
        for (int p = 0; p < 4; ++p) {
            v2f a = o2v[r][p] - mm2;
            v2f e; e[0] = exp2_fast(a[0]); e[1] = exp2_fast(a[1]);
            se += e;
            v2f xp; xp[0]=xs[r][8+2*p]; xp[1]=xs[r][9+2*p];
            de += xp * e;
        }
        if (valid[r]) out[b0 + r * 256] = (de[0] + de[1]) * rcpf(se[0] + se[1]);
    }
}

extern "C" void kernel_launch(void* const* d_in, const int* in_sizes, int n_in,
                              void* d_out, int out_size, void* d_ws, size_t ws_size,
                              hipStream_t stream) {
    const float* x  = (const float*)d_in[0];
    const float* wq = (const float*)d_in[1];
    const float* wk = (const float*)d_in[2];
    const float* wv = (const float*)d_in[3];
    const float* Wh = (const float*)d_in[4];
    const float* bh = (const float*)d_in[5];
    const float* Wo = (const float*)d_in[6];
    const float* bo = (const float*)d_in[7];
    float* out = (float*)d_out;

    const int B = in_sizes[0] / 16;
    const int block = 256;
    const int rows_per_block = block * ROWS;
    const int grid = (B + rows_per_block - 1) / rows_per_block;
    fused_attn_mlp<<<grid, block, 0, stream>>>(x, wq, wk, wv, Wh, bh, Wo, bo, out, B);
}